// Round 1
// baseline (232.246 us; speedup 1.0000x reference)
//
#include <hip/hip_runtime.h>
#include <stdint.h>

#define V 257
#define NB 64
#define L 1024
#define ZERO_STATE 257   // table slot for the all-zero prev vector

// K0: per-state transition table. entry = loc_idx | (ia << 16); ia==0 encodes "output zero vector".
__global__ void build_table(const float* __restrict__ W, const float* __restrict__ bias,
                            const int* __restrict__ inv_table, uint32_t* __restrict__ gtable) {
    int p = blockIdx.x;          // 0..257 ; 257 = zero state (net = bias only)
    int lane = threadIdx.x;      // 64 threads = 1 wave
    const float* wrow = (p < V) ? (W + (size_t)p * (2 * V)) : nullptr;
    float bestL = -INFINITY; int idxL = 0;
    float bestS = -INFINITY; int idxS = 0;
    for (int j = lane; j < V; j += 64) {
        float vl = wrow ? (wrow[j] + bias[j]) : bias[j];
        float vs = wrow ? (wrow[V + j] + bias[V + j]) : bias[V + j];
        if (vl > bestL) { bestL = vl; idxL = j; }   // ascending j => strict > keeps first max
        if (vs > bestS) { bestS = vs; idxS = j; }
    }
    // wave-64 reduce with first-index tie-break (matches jnp.argmax)
    for (int off = 32; off >= 1; off >>= 1) {
        float oL = __shfl_down(bestL, off); int oiL = __shfl_down(idxL, off);
        float oS = __shfl_down(bestS, off); int oiS = __shfl_down(idxS, off);
        if (oL > bestL || (oL == bestL && oiL < idxL)) { bestL = oL; idxL = oiL; }
        if (oS > bestS || (oS == bestS && oiS < idxS)) { bestS = oS; idxS = oiS; }
    }
    if (lane == 0) {
        int ia = inv_table[idxS];   // inv_table[0] == 0  <=>  scale argmax hit 0
        gtable[p] = (uint32_t)idxL | ((uint32_t)ia << 16);
    }
}

// K1: extract one-hot index per (b,t) row from x. one_hot produces exact 1.0f.
__global__ void extract_idx(const float4* __restrict__ x4, uint16_t* __restrict__ xidx, int n4) {
    int stride = gridDim.x * blockDim.x;
    for (int i = blockIdx.x * blockDim.x + threadIdx.x; i < n4; i += stride) {
        float4 v = x4[i];
        int j = i * 4;
        if (v.x == 1.0f) { int r = j / V;       xidx[r] = (uint16_t)(j     - r * V); }
        if (v.y == 1.0f) { int r = (j + 1) / V; xidx[r] = (uint16_t)(j + 1 - r * V); }
        if (v.z == 1.0f) { int r = (j + 2) / V; xidx[r] = (uint16_t)(j + 2 - r * V); }
        if (v.w == 1.0f) { int r = (j + 3) / V; xidx[r] = (uint16_t)(j + 3 - r * V); }
    }
}

// K2: sequential 1024-step chase, one block (one wave) per batch. Lane 0 walks the chain.
__global__ void chase(const uint32_t* __restrict__ gtable, const uint16_t* __restrict__ xidx,
                      uint16_t* __restrict__ oidx) {
    __shared__ uint32_t tbl[258];
    __shared__ uint16_t xs[L];
    __shared__ uint16_t os[L];
    int b = blockIdx.x, tid = threadIdx.x;
    for (int j = tid; j < 258; j += 64) tbl[j] = gtable[j];
    for (int j = tid; j < L; j += 64) xs[j] = xidx[b * L + j];
    __syncthreads();
    if (tid == 0) {
        int p = ZERO_STATE;
        for (int t = 0; t < L; ++t) {
            uint32_t e = tbl[p];
            int ia  = (int)(e >> 16);
            int loc = (int)(e & 0xffff);
            int x = xs[t];
            if (ia == 0) {            // scale argmax == 0 -> output is the zero vector
                os[t] = 0xFFFF;
                p = ZERO_STATE;
            } else {
                int s = x - loc;              // (-257, 257)
                s += (s >> 31) & V;           // mod V -> [0,256]
                int n = s * ia;               // <= 65536
                int m = (n & 255) - (n >> 8); // 256 == -1 (mod 257) fold -> [-256,255]
                m += (m >> 31) & V;           // -> [0,256]
                os[t] = (uint16_t)m;
                p = m;
            }
        }
    }
    __syncthreads();
    for (int j = tid; j < L; j += 64) oidx[b * L + j] = os[j];
}

// K3: write one-hot output (67 MB), float4 stores, 0xFFFF sentinel -> all-zero row.
__global__ void write_out(const uint16_t* __restrict__ oidx, float4* __restrict__ out, int n4) {
    int stride = gridDim.x * blockDim.x;
    for (int i = blockIdx.x * blockDim.x + threadIdx.x; i < n4; i += stride) {
        int j = i * 4;
        float4 v;
        {
            int r = j / V;       int c = j - r * V;       v.x = (c == (int)oidx[r]) ? 1.0f : 0.0f;
        }
        {
            int jj = j + 1; int r = jj / V; int c = jj - r * V; v.y = (c == (int)oidx[r]) ? 1.0f : 0.0f;
        }
        {
            int jj = j + 2; int r = jj / V; int c = jj - r * V; v.z = (c == (int)oidx[r]) ? 1.0f : 0.0f;
        }
        {
            int jj = j + 3; int r = jj / V; int c = jj - r * V; v.w = (c == (int)oidx[r]) ? 1.0f : 0.0f;
        }
        out[i] = v;
    }
}

extern "C" void kernel_launch(void* const* d_in, const int* in_sizes, int n_in,
                              void* d_out, int out_size, void* d_ws, size_t ws_size,
                              hipStream_t stream) {
    const float* x    = (const float*)d_in[0];   // [B, L, V] one-hot f32
    const float* W    = (const float*)d_in[1];   // [V, 2V]
    const float* bias = (const float*)d_in[2];   // [2V]
    const int*   inv  = (const int*)d_in[3];     // [V]
    float* out = (float*)d_out;

    uint8_t* ws = (uint8_t*)d_ws;
    uint32_t* gtable = (uint32_t*)ws;                         // 258 * 4 B
    uint16_t* xidx   = (uint16_t*)(ws + 4096);                // 64*1024 * 2 B
    uint16_t* oidx   = (uint16_t*)(ws + 4096 + NB * L * 2);   // 64*1024 * 2 B

    int n4 = NB * L * V / 4;   // 4,210,688 exact

    build_table<<<258, 64, 0, stream>>>(W, bias, inv, gtable);
    extract_idx<<<2048, 256, 0, stream>>>((const float4*)x, xidx, n4);
    chase<<<NB, 64, 0, stream>>>(gtable, xidx, oidx);
    write_out<<<2048, 256, 0, stream>>>(oidx, (float4*)out, n4);
}

// Round 2
// 141.328 us; speedup vs baseline: 1.6433x; 1.6433x over previous
//
#include <hip/hip_runtime.h>
#include <stdint.h>

#define V 257
#define NB 64
#define L 1024
#define ZERO_STATE 257   // table slot for the all-zero prev vector
#define NSTATE 258
#define CHUNKS 32        // C
#define CLEN 32          // K ; C*K == L

// transition: given state p and input index x, produce next state (== output index,
// with ZERO_STATE meaning "output is the all-zero vector").
__device__ __forceinline__ int gstep(const uint32_t* __restrict__ tbl, int p, int x) {
    uint32_t e = tbl[p];
    int ia  = (int)(e >> 16);
    int loc = (int)(e & 0xffff);
    int s = x - loc;               // (-257, 257)
    s += (s >> 31) & V;            // mod V -> [0,256]
    int n = s * ia;                // <= 65536
    int m = (n & 255) - (n >> 8);  // 256 == -1 (mod 257) fold -> [-256,255]
    m += (m >> 31) & V;            // -> [0,256]
    return (ia == 0) ? ZERO_STATE : m;
}

// K0: per-state transition table. entry = loc_idx | (ia << 16); ia==0 encodes "zero vector out".
__global__ void build_table(const float* __restrict__ W, const float* __restrict__ bias,
                            const int* __restrict__ inv_table, uint32_t* __restrict__ gtable) {
    int p = blockIdx.x;          // 0..257 ; 257 = zero state (net = bias only)
    int lane = threadIdx.x;      // 64 threads = 1 wave
    const float* wrow = (p < V) ? (W + (size_t)p * (2 * V)) : nullptr;
    float bestL = -INFINITY; int idxL = 0;
    float bestS = -INFINITY; int idxS = 0;
    for (int j = lane; j < V; j += 64) {
        float vl = wrow ? (wrow[j] + bias[j]) : bias[j];
        float vs = wrow ? (wrow[V + j] + bias[V + j]) : bias[V + j];
        if (vl > bestL) { bestL = vl; idxL = j; }   // ascending j => strict > keeps first max
        if (vs > bestS) { bestS = vs; idxS = j; }
    }
    for (int off = 32; off >= 1; off >>= 1) {
        float oL = __shfl_down(bestL, off); int oiL = __shfl_down(idxL, off);
        float oS = __shfl_down(bestS, off); int oiS = __shfl_down(idxS, off);
        if (oL > bestL || (oL == bestL && oiL < idxL)) { bestL = oL; idxL = oiL; }
        if (oS > bestS || (oS == bestS && oiS < idxS)) { bestS = oS; idxS = oiS; }
    }
    if (lane == 0) {
        int ia = inv_table[idxS];   // inv_table[0] == 0  <=>  scale argmax hit 0
        gtable[p] = (uint32_t)idxL | ((uint32_t)ia << 16);
    }
}

// K1: extract one-hot index per (b,t) row from x. one_hot produces exact 1.0f.
__global__ void extract_idx(const float4* __restrict__ x4, uint16_t* __restrict__ xidx, int n4) {
    int stride = gridDim.x * blockDim.x;
    for (int i = blockIdx.x * blockDim.x + threadIdx.x; i < n4; i += stride) {
        float4 v = x4[i];
        int j = i * 4;
        if (v.x == 1.0f) { int r = j / V;       xidx[r] = (uint16_t)(j     - r * V); }
        if (v.y == 1.0f) { int r = (j + 1) / V; xidx[r] = (uint16_t)(j + 1 - r * V); }
        if (v.z == 1.0f) { int r = (j + 2) / V; xidx[r] = (uint16_t)(j + 2 - r * V); }
        if (v.w == 1.0f) { int r = (j + 3) / V; xidx[r] = (uint16_t)(j + 3 - r * V); }
    }
}

// K2: speculative chunk functions. One block per (batch, chunk); 128 threads, each
// walking 3 independent start-state chains (3*128=384 >= 258, extras clamped/dummy).
__global__ void phase1(const uint32_t* __restrict__ gtable, const uint16_t* __restrict__ xidx,
                       uint16_t* __restrict__ f) {
    __shared__ uint32_t tbl[NSTATE];
    __shared__ uint16_t xs[CLEN];
    int bc = blockIdx.x;
    int b = bc / CHUNKS, c = bc % CHUNKS;
    int tid = threadIdx.x;
    for (int j = tid; j < NSTATE; j += 128) tbl[j] = gtable[j];
    if (tid < CLEN) xs[tid] = xidx[b * L + c * CLEN + tid];
    __syncthreads();
    int p0 = tid;
    int p1 = tid + 128;
    int p2 = (tid + 256 < NSTATE) ? tid + 256 : 0;   // dummy chain for tid >= 2
    #pragma unroll 4
    for (int k = 0; k < CLEN; ++k) {
        int x = xs[k];
        p0 = gstep(tbl, p0, x);
        p1 = gstep(tbl, p1, x);
        p2 = gstep(tbl, p2, x);
    }
    uint16_t* frow = f + (size_t)bc * NSTATE;
    frow[tid] = (uint16_t)p0;
    frow[tid + 128] = (uint16_t)p1;
    if (tid < 2) frow[tid + 256] = (uint16_t)p2;
}

// K3: per batch — compose chunk functions serially (32 deps) then replay all chunks
// in parallel (32 lanes x 32 steps) emitting output indices.
__global__ void phase23(const uint32_t* __restrict__ gtable, const uint16_t* __restrict__ xidx,
                        const uint16_t* __restrict__ f, uint16_t* __restrict__ oidx) {
    __shared__ uint32_t tbl[NSTATE];
    __shared__ uint16_t fl[CHUNKS * NSTATE];
    __shared__ uint16_t xs[L];
    __shared__ uint16_t os[L];
    __shared__ uint16_t entry[CHUNKS];
    int b = blockIdx.x, tid = threadIdx.x;
    for (int j = tid; j < NSTATE; j += 256) tbl[j] = gtable[j];
    for (int j = tid; j < CHUNKS * NSTATE; j += 256) fl[j] = f[(size_t)b * CHUNKS * NSTATE + j];
    for (int j = tid; j < L; j += 256) xs[j] = xidx[b * L + j];
    __syncthreads();
    if (tid == 0) {
        int st = ZERO_STATE;
        for (int c = 0; c < CHUNKS; ++c) { entry[c] = (uint16_t)st; st = fl[c * NSTATE + st]; }
    }
    __syncthreads();
    if (tid < CHUNKS) {
        int p = entry[tid];
        int base = tid * CLEN;
        for (int k = 0; k < CLEN; ++k) {
            int x = xs[base + k];
            uint32_t e = tbl[p];
            int ia  = (int)(e >> 16);
            int loc = (int)(e & 0xffff);
            if (ia == 0) {
                os[base + k] = 0xFFFF;
                p = ZERO_STATE;
            } else {
                int s = x - loc;
                s += (s >> 31) & V;
                int n = s * ia;
                int m = (n & 255) - (n >> 8);
                m += (m >> 31) & V;
                os[base + k] = (uint16_t)m;
                p = m;
            }
        }
    }
    __syncthreads();
    for (int j = tid; j < L; j += 256) oidx[b * L + j] = os[j];
}

// K4: write one-hot output (67 MB), float4 stores, 0xFFFF sentinel -> all-zero row.
__global__ void write_out(const uint16_t* __restrict__ oidx, float4* __restrict__ out, int n4) {
    int stride = gridDim.x * blockDim.x;
    for (int i = blockIdx.x * blockDim.x + threadIdx.x; i < n4; i += stride) {
        int j = i * 4;
        float4 v;
        { int r = j / V;            int c = j - r * V;      v.x = (c == (int)oidx[r]) ? 1.0f : 0.0f; }
        { int jj = j + 1; int r = jj / V; int c = jj - r * V; v.y = (c == (int)oidx[r]) ? 1.0f : 0.0f; }
        { int jj = j + 2; int r = jj / V; int c = jj - r * V; v.z = (c == (int)oidx[r]) ? 1.0f : 0.0f; }
        { int jj = j + 3; int r = jj / V; int c = jj - r * V; v.w = (c == (int)oidx[r]) ? 1.0f : 0.0f; }
        out[i] = v;
    }
}

extern "C" void kernel_launch(void* const* d_in, const int* in_sizes, int n_in,
                              void* d_out, int out_size, void* d_ws, size_t ws_size,
                              hipStream_t stream) {
    const float* x    = (const float*)d_in[0];   // [B, L, V] one-hot f32
    const float* W    = (const float*)d_in[1];   // [V, 2V]
    const float* bias = (const float*)d_in[2];   // [2V]
    const int*   inv  = (const int*)d_in[3];     // [V]
    float* out = (float*)d_out;

    uint8_t* ws = (uint8_t*)d_ws;
    uint32_t* gtable = (uint32_t*)ws;                                   // 258*4 B (4 KB slot)
    uint16_t* xidx   = (uint16_t*)(ws + 4096);                          // 64*1024*2 B
    uint16_t* oidx   = (uint16_t*)(ws + 4096 + NB * L * 2);             // 64*1024*2 B
    uint16_t* f      = (uint16_t*)(ws + 4096 + 2 * NB * L * 2);         // 64*32*258*2 B ~ 1.06 MB

    int n4 = NB * L * V / 4;   // 4,210,688 exact

    build_table<<<NSTATE, 64, 0, stream>>>(W, bias, inv, gtable);
    extract_idx<<<2048, 256, 0, stream>>>((const float4*)x, xidx, n4);
    phase1<<<NB * CHUNKS, 128, 0, stream>>>(gtable, xidx, f);
    phase23<<<NB, 256, 0, stream>>>(gtable, xidx, f, oidx);
    write_out<<<2048, 256, 0, stream>>>(oidx, (float4*)out, n4);
}